// Round 1
// 330.132 us; speedup vs baseline: 1.2223x; 1.2223x over previous
//
#include <hip/hip_runtime.h>
#include <hip/hip_bf16.h>

// 2-layer GraphSAGE mean-aggr, N=100000, E=1600000, F=128.
// R11: eliminate hist_kernel (65us, 50MB atomic write-through: 1.6M global
// atomics x ~32B/atomic to HBM). Degree + rowptr are now computed inside the
// bucket pipeline with LDS atomics: bucket_scan emits bucket-relative bases +
// per-bucket totals; a 1-block scan builds bucket_base[]; bucket_fill
// histograms its 128 node slots from staging (pass 1), scans, writes
// rowptr/deg_i, then fills csr_src (pass 2). partial_sum/scan_partial/rowptr
// kernels and the deg memset are gone. csr_mean + MFMA GEMMs byte-identical
// to R10 (single logical change).

#define N_NODES 100000
#define N_EDGES 1600000
#define F 128
#define MPITCH 256    // mean row pitch in bf16 elems (interleaved in d_out)
#define NBK 782       // ceil(N/128) buckets (128 nodes each)
#define NSB 391       // scatter blocks (4096 edges each)

typedef __attribute__((ext_vector_type(8))) short short8;
typedef __attribute__((ext_vector_type(4))) float f32x4;

__device__ __forceinline__ unsigned short f2bf(float f) {
    union { __hip_bfloat16 h; unsigned short u; } cv;
    cv.h = __float2bfloat16(f);
    return cv.u;
}
__device__ __forceinline__ float bf2f(unsigned short u) {
    return __uint_as_float(((unsigned)u) << 16);
}
// unpack packed bf16 pair and accumulate
__device__ __forceinline__ void upadd(unsigned u, float& a, float& b) {
    a += __uint_as_float(u << 16);
    b += __uint_as_float(u & 0xffff0000u);
}

// ---------------- contention-free bucket permute (R7-proven, R11-extended) ----------------
__global__ __launch_bounds__(256) void blkhist_kernel(
    const int* __restrict__ dst, int* __restrict__ blkhist, int E)
{
    __shared__ int h[NBK];
    int t = threadIdx.x, blk = blockIdx.x;
    for (int i = t; i < NBK; i += 256) h[i] = 0;
    __syncthreads();
    int base = blk * 4096;
    int end = min(base + 4096, E);
    for (int e = base + t; e < end; e += 256) atomicAdd(&h[dst[e] >> 7], 1);
    __syncthreads();
    for (int i = t; i < NBK; i += 256) blkhist[blk * NBK + i] = h[i];
}

// per-bucket: scan over scatter blocks -> bucket-RELATIVE block bases; emit total
__global__ __launch_bounds__(512) void bucket_scan_kernel(
    const int* __restrict__ blkhist, int* __restrict__ bbase,
    int* __restrict__ btotal)
{
    __shared__ int s[512];
    int b = blockIdx.x, t = threadIdx.x;
    int v = (t < NSB) ? blkhist[t * NBK + b] : 0;
    s[t] = v;
    __syncthreads();
#pragma unroll
    for (int off = 1; off < 512; off <<= 1) {
        int u = (t >= off) ? s[t - off] : 0;
        __syncthreads();
        s[t] += u;
        __syncthreads();
    }
    if (t < NSB) bbase[t * NBK + b] = s[t] - v;   // relative to bucket start
    if (t == NSB - 1) btotal[b] = s[t];           // bucket total
}

// single block: exclusive scan of bucket totals in-place; bb[NBK] = E sentinel
__global__ __launch_bounds__(1024) void bucket_base_scan_kernel(int* bb)
{
    __shared__ int s[1024];
    int t = threadIdx.x;
    int v = (t < NBK) ? bb[t] : 0;
    s[t] = v;
    __syncthreads();
#pragma unroll
    for (int off = 1; off < 1024; off <<= 1) {
        int u = (t >= off) ? s[t - off] : 0;
        __syncthreads();
        s[t] += u;
        __syncthreads();
    }
    if (t <= NBK) bb[t] = (t == 0) ? 0 : s[t - 1];
}

__global__ __launch_bounds__(256) void bucket_scatter_kernel(
    const int* __restrict__ src, const int* __restrict__ dst,
    const int* __restrict__ bbase, const int* __restrict__ bucket_base,
    unsigned* __restrict__ staging, int E)
{
    __shared__ int cur[NBK];
    int t = threadIdx.x, blk = blockIdx.x;
    for (int i = t; i < NBK; i += 256)
        cur[i] = bbase[blk * NBK + i] + bucket_base[i];
    __syncthreads();
    int base = blk * 4096;
    int end = min(base + 4096, E);
    for (int e = base + t; e < end; e += 256) {
        int d = dst[e];
        int p = atomicAdd(&cur[d >> 7], 1);
        staging[p] = ((unsigned)src[e] << 7) | (unsigned)(d & 127);
    }
}

// pass 1: LDS-histogram the bucket's 128 node slots -> deg/rowptr; pass 2: fill
__global__ __launch_bounds__(256) void bucket_fill_kernel(
    const unsigned* __restrict__ staging, const int* __restrict__ bucket_base,
    int* __restrict__ rowptr, int* __restrict__ deg_i,
    int* __restrict__ csr_src, int N)
{
    __shared__ int cnt[128];
    __shared__ int sc[128];
    __shared__ int cur[128];
    int b = blockIdx.x;
    int t = threadIdx.x;
    if (t < 128) cnt[t] = 0;
    __syncthreads();
    int start = bucket_base[b];
    int end = bucket_base[b + 1];
    for (int e = start + t; e < end; e += 256)
        atomicAdd(&cnt[staging[e] & 127], 1);
    __syncthreads();
    // exclusive scan over 128 slot counts
    if (t < 128) sc[t] = cnt[t];
    __syncthreads();
#pragma unroll
    for (int off = 1; off < 128; off <<= 1) {
        int v = (t < 128 && t >= off) ? sc[t - off] : 0;
        __syncthreads();
        if (t < 128) sc[t] += v;
        __syncthreads();
    }
    if (t < 128) {
        int excl = sc[t] - cnt[t];
        cur[t] = start + excl;
        int node = (b << 7) + t;
        if (node < N) {
            rowptr[node] = start + excl;
            deg_i[node] = cnt[t];
        }
    }
    __syncthreads();
    for (int e = start + t; e < end; e += 256) {
        unsigned u = staging[e];
        int p = atomicAdd(&cur[u & 127], 1);
        csr_src[p] = (int)(u >> 7);
    }
}

// ---------------- weight transpose+cast: Wt[layer][col][k] bf16 ----------------
__global__ __launch_bounds__(256) void wt_kernel(
    const float* __restrict__ Wl1, const float* __restrict__ Wr1,
    const float* __restrict__ Wl2, const float* __restrict__ Wr2,
    unsigned short* __restrict__ wt)
{
    int e = blockIdx.x * 256 + threadIdx.x;   // 0..65535
    int layer = e >> 15;
    int idx = e & 32767;
    int k = idx >> 7;      // 0..255
    int c = idx & 127;
    const float* W = (layer == 0) ? (k < 128 ? Wl1 : Wr1)
                                  : (k < 128 ? Wl2 : Wr2);
    float v = W[(k & 127) * 128 + c];
    wt[layer * 32768 + c * 256 + k] = f2bf(v);
}

// ---------------- cast x -> bf16 ----------------
__global__ __launch_bounds__(256) void cast_kernel(
    const float* __restrict__ x, unsigned short* __restrict__ xb, int total4)
{
    int i = blockIdx.x * 256 + threadIdx.x;
    if (i >= total4) return;
    float4 v = ((const float4*)x)[i];
    unsigned lo = ((unsigned)f2bf(v.y) << 16) | f2bf(v.x);
    unsigned hi = ((unsigned)f2bf(v.w) << 16) | f2bf(v.z);
    ((uint2*)xb)[i] = make_uint2(lo, hi);
}

// ---------------- aggregate: mean over in-neighbors (bf16 src) ----------------
// 1 node/wave; quarter-wave q handles edge e+q; lane c=(lane&15) loads 16B
// (8 bf16 cols) of the neighbor row. Unroll-2 -> 2KB/wave in flight.
// Final: shfl_xor(16,32) cross-quarter reduce; q==0 lanes store 16B.
// Output: bf16 mean interleaved, row pitch MPITCH (256B used per 512B slot).
__global__ __launch_bounds__(256) void csr_mean_kernel(
    const uint4* __restrict__ featb4, const int* __restrict__ rowptr,
    const int* __restrict__ deg_i, const int* __restrict__ csr_src,
    uint4* __restrict__ mean4, int N)
{
    int n = blockIdx.x * 4 + (threadIdx.x >> 6);
    int lane = threadIdx.x & 63;
    int q = lane >> 4;        // edge slot 0..3
    int c = lane & 15;        // 16B column segment
    if (n >= N) return;
    int start = rowptr[n];
    int dg = deg_i[n];
    int end = start + dg;

    float acc[8];
#pragma unroll
    for (int j = 0; j < 8; ++j) acc[j] = 0.f;

    for (int e = start; e < end; e += 8) {
        int i0 = e + q;
        int i1 = e + 4 + q;
        uint4 u0 = make_uint4(0, 0, 0, 0);
        uint4 u1 = make_uint4(0, 0, 0, 0);
        if (i0 < end) u0 = featb4[(size_t)csr_src[i0] * 16 + c];
        if (i1 < end) u1 = featb4[(size_t)csr_src[i1] * 16 + c];
        upadd(u0.x, acc[0], acc[1]);
        upadd(u0.y, acc[2], acc[3]);
        upadd(u0.z, acc[4], acc[5]);
        upadd(u0.w, acc[6], acc[7]);
        upadd(u1.x, acc[0], acc[1]);
        upadd(u1.y, acc[2], acc[3]);
        upadd(u1.z, acc[4], acc[5]);
        upadd(u1.w, acc[6], acc[7]);
    }

    // cross-quarter reduction: lanes c, c+16, c+32, c+48 hold partials of cols 8c..8c+7
#pragma unroll
    for (int j = 0; j < 8; ++j) {
        acc[j] += __shfl_xor(acc[j], 16);
        acc[j] += __shfl_xor(acc[j], 32);
    }

    if (q == 0) {
        float r = 1.0f / fmaxf((float)dg, 1.0f);
        uint4 o;
        o.x = ((unsigned)f2bf(acc[1] * r) << 16) | f2bf(acc[0] * r);
        o.y = ((unsigned)f2bf(acc[3] * r) << 16) | f2bf(acc[2] * r);
        o.z = ((unsigned)f2bf(acc[5] * r) << 16) | f2bf(acc[4] * r);
        o.w = ((unsigned)f2bf(acc[7] * r) << 16) | f2bf(acc[6] * r);
        mean4[(size_t)n * (MPITCH / 8) + c] = o;
    }
}

// ---------------- MFMA GEMM: out = [mean|x] @ Wt^T + bias (+relu) ----------------
// 256 thr = 4 waves; block computes 64 rows x 128 cols; K=256 in 4 chunks.
// meanb: bf16, row pitch MPITCH (interleaved in d_out). xin: bf16, pitch F.
// Aliasing-safe: block reads ONLY its own rows of meanb/xin; epilogue writes
// those same rows after all reads (ordered by __syncthreads within block).
template <bool RELU, bool OUT_BF16>
__global__ __launch_bounds__(256) void sage_gemm_mfma(
    const unsigned short* __restrict__ meanb,
    const unsigned short* __restrict__ xin,
    const unsigned short* __restrict__ wt,   // [128 cols][256 k] bf16
    const float* __restrict__ bias,
    float* __restrict__ outp, unsigned short* __restrict__ outb, int N)
{
    __shared__ unsigned short As[64][72];    // stride 144 B: 16B-aligned, conflict-free b128
    __shared__ unsigned short Bs[128][72];

    const int t = threadIdx.x;
    const int block_row = blockIdx.x * 64;
    const int lane = t & 63;
    const int w = t >> 6;
    const int m = lane & 15;
    const int kq = lane >> 4;

    f32x4 acc[8];
#pragma unroll
    for (int i = 0; i < 8; ++i) acc[i] = (f32x4){0.f, 0.f, 0.f, 0.f};

    for (int chunk = 0; chunk < 4; ++chunk) {
        const bool is_mean = (chunk < 2);
        const int kbase = (chunk & 1) * 64;

        // ---- A tile: 64 rows x 64 k (each thread: 16 bf16 = 32 B) ----
        {
            int row_l = t >> 2;
            int seg = t & 3;
            int grow = block_row + row_l;
            unsigned short* dstp = &As[row_l][seg * 16];
            if (grow < N) {
                const unsigned short* srcp = is_mean
                    ? meanb + (size_t)grow * MPITCH + kbase + seg * 16
                    : xin   + (size_t)grow * F      + kbase + seg * 16;
                const uint4* p = (const uint4*)srcp;
                ((uint4*)dstp)[0] = p[0];
                ((uint4*)dstp)[1] = p[1];
            } else {
                uint4 z = make_uint4(0, 0, 0, 0);
                ((uint4*)dstp)[0] = z;
                ((uint4*)dstp)[1] = z;
            }
        }
        // ---- B tile: 128 cols x 64 k from Wt (each thread: 32 bf16 = 64 B) ----
        {
            int c = t >> 1;
            int half = t & 1;
            const uint4* p = (const uint4*)(wt + c * 256 + chunk * 64 + half * 32);
            unsigned short* dstp = &Bs[c][half * 32];
            ((uint4*)dstp)[0] = p[0];
            ((uint4*)dstp)[1] = p[1];
            ((uint4*)dstp)[2] = p[2];
            ((uint4*)dstp)[3] = p[3];
        }
        __syncthreads();

        // ---- MFMA: A[m=lane&15][k=(lane>>4)*8+j], B[k][n=lane&15] ----
#pragma unroll
        for (int ks = 0; ks < 2; ++ks) {
            short8 a = *(const short8*)&As[w * 16 + m][ks * 32 + kq * 8];
#pragma unroll
            for (int tt = 0; tt < 8; ++tt) {
                short8 b = *(const short8*)&Bs[tt * 16 + m][ks * 32 + kq * 8];
                acc[tt] = __builtin_amdgcn_mfma_f32_16x16x32_bf16(a, b, acc[tt], 0, 0, 0);
            }
        }
        __syncthreads();
    }

    // ---- epilogue: C/D row=(lane>>4)*4+reg, col=lane&15 ----
    float bb[8];
#pragma unroll
    for (int tt = 0; tt < 8; ++tt) bb[tt] = bias[tt * 16 + m];
    int rbase = block_row + w * 16 + kq * 4;
#pragma unroll
    for (int r = 0; r < 4; ++r) {
        int grow = rbase + r;
        if (grow < N) {
#pragma unroll
            for (int tt = 0; tt < 8; ++tt) {
                float v = acc[tt][r] + bb[tt];
                if (RELU) v = fmaxf(v, 0.f);
                if (OUT_BF16)
                    outb[(size_t)grow * F + tt * 16 + m] = f2bf(v);
                else
                    outp[(size_t)grow * F + tt * 16 + m] = v;
            }
        }
    }
}

extern "C" void kernel_launch(void* const* d_in, const int* in_sizes, int n_in,
                              void* d_out, int out_size, void* d_ws, size_t ws_size,
                              hipStream_t stream) {
    const float* x    = (const float*)d_in[0];
    const int*   ei   = (const int*)d_in[1];    // int32 (harness converts int64)
    const float* W_l1 = (const float*)d_in[2];
    const float* W_r1 = (const float*)d_in[3];
    const float* b1   = (const float*)d_in[4];
    const float* W_l2 = (const float*)d_in[5];
    const float* W_r2 = (const float*)d_in[6];
    const float* b2   = (const float*)d_in[7];
    float* out        = (float*)d_out;

    const int N = N_NODES;
    const int E = N_EDGES;
    const int* srcv = ei;
    const int* dstv = ei + E;

    // ---- workspace layout (bytes); ws_size proven >= 33,337,344 ----
    const size_t rowptr_off = 400128;            // int[N]
    const size_t bb_off     = 800256;            // bucket_base int[NBK+1] (4096 reserved)
    const size_t csr_off    = 804352;            // int[1.6M] = 6.4 MB -> 7,204,352
    const size_t xb_off     = 7204352;           // bf16[N*F] = 25.6 MB -> 32,804,352
    const size_t wt_off     = 32804352;          // bf16[2][128][256] -> 32,935,424
    const size_t need_min   = 32935424;          // < proven 33,337,344
    // transients aliased into xb region (consumed by bucket_fill before cast):
    const size_t blkh_rel   = 0;                 // int[NSB*NBK]
    const size_t bbase_rel  = 1223168;           // int[NSB*NBK]
    const size_t stag_rel   = 2446336;           // uint[1.6M] -> 8,846,336 (< 25.6MB)

    if (ws_size < need_min) return;  // clean validation failure as diagnostic

    char* ws = (char*)d_ws;
    int* deg_i   = (int*)ws;
    int* rowptr  = (int*)(ws + rowptr_off);
    int* bucket_base = (int*)(ws + bb_off);
    int* csr_src = (int*)(ws + csr_off);
    unsigned short* xb = (unsigned short*)(ws + xb_off);
    int* blkhist = (int*)(ws + xb_off + blkh_rel);
    int* bbase   = (int*)(ws + xb_off + bbase_rel);
    unsigned* staging = (unsigned*)(ws + xb_off + stag_rel);
    unsigned short* wt = (unsigned short*)(ws + wt_off);
    // means live interleaved in d_out: row n -> bytes [n*512, n*512+256)
    uint4* mean4 = (uint4*)d_out;
    const unsigned short* meanb = (const unsigned short*)d_out;

    // ---- contention-free bucket permute -> csr_src (+deg/rowptr fused) ----
    blkhist_kernel<<<dim3(NSB), dim3(256), 0, stream>>>(dstv, blkhist, E);
    bucket_scan_kernel<<<dim3(NBK), dim3(512), 0, stream>>>(blkhist, bbase, bucket_base);
    bucket_base_scan_kernel<<<dim3(1), dim3(1024), 0, stream>>>(bucket_base);
    bucket_scatter_kernel<<<dim3(NSB), dim3(256), 0, stream>>>(
        srcv, dstv, bbase, bucket_base, staging, E);
    bucket_fill_kernel<<<dim3(NBK), dim3(256), 0, stream>>>(
        staging, bucket_base, rowptr, deg_i, csr_src, N);

    // ---- weight prep + x cast (after staging consumed) ----
    wt_kernel<<<dim3(256), dim3(256), 0, stream>>>(W_l1, W_r1, W_l2, W_r2, wt);
    cast_kernel<<<dim3((N * F / 4 + 255) / 256), dim3(256), 0, stream>>>(x, xb, N * F / 4);

    dim3 ablock(256), agrid((N + 3) / 4);
    dim3 gblock(256), ggrid((N + 63) / 64);

    // ---- layer 1: mean1(xb) -> d_out interleaved; gemm1 -> h bf16 into xb ----
    csr_mean_kernel<<<agrid, ablock, 0, stream>>>(
        (const uint4*)xb, rowptr, deg_i, csr_src, mean4, N);
    sage_gemm_mfma<true, true><<<ggrid, gblock, 0, stream>>>(
        meanb, xb, wt, b1, nullptr, xb, N);

    // ---- layer 2: mean2(xb=h) -> d_out interleaved; gemm2 -> fp32 d_out ----
    csr_mean_kernel<<<agrid, ablock, 0, stream>>>(
        (const uint4*)xb, rowptr, deg_i, csr_src, mean4, N);
    sage_gemm_mfma<false, false><<<ggrid, gblock, 0, stream>>>(
        meanb, xb, wt + 32768, b2, out, nullptr, N);
}

// Round 2
// 315.229 us; speedup vs baseline: 1.2801x; 1.0473x over previous
//
#include <hip/hip_runtime.h>
#include <hip/hip_bf16.h>

// 2-layer GraphSAGE mean-aggr, N=100000, E=1600000, F=128.
// R12: csr_mean latency restructure. R11 counters: 65us/dispatch, 40% HBM,
// 48% VALU, 70% occ -> two serialized memory round-trips per 8-edge iter
// (csr_src load then gather) + exec-mask/cndmask churn from conditional
// gathers. Now: one coalesced 64-index load per wave (lane l takes
// csr_src[start+l]), per-edge indices distributed via __shfl (ds_bpermute,
// no global round-trip); main loop 16 edges/iter, 4 independent unchecked
// gathers (4KB/wave in flight); predicated 4-edge tail; 32-bit gather
// addressing (i<<4)|c. Accumulation order per register is IDENTICAL to
// R10/R11 (edges q,q+4,q+8,...) -> bit-identical output.
// Everything else byte-identical to R11.

#define N_NODES 100000
#define N_EDGES 1600000
#define F 128
#define MPITCH 256    // mean row pitch in bf16 elems (interleaved in d_out)
#define NBK 782       // ceil(N/128) buckets (128 nodes each)
#define NSB 391       // scatter blocks (4096 edges each)

typedef __attribute__((ext_vector_type(8))) short short8;
typedef __attribute__((ext_vector_type(4))) float f32x4;

__device__ __forceinline__ unsigned short f2bf(float f) {
    union { __hip_bfloat16 h; unsigned short u; } cv;
    cv.h = __float2bfloat16(f);
    return cv.u;
}
__device__ __forceinline__ float bf2f(unsigned short u) {
    return __uint_as_float(((unsigned)u) << 16);
}
// unpack packed bf16 pair and accumulate
__device__ __forceinline__ void upadd(unsigned u, float& a, float& b) {
    a += __uint_as_float(u << 16);
    b += __uint_as_float(u & 0xffff0000u);
}

// ---------------- contention-free bucket permute (R7-proven, R11-extended) ----------------
__global__ __launch_bounds__(256) void blkhist_kernel(
    const int* __restrict__ dst, int* __restrict__ blkhist, int E)
{
    __shared__ int h[NBK];
    int t = threadIdx.x, blk = blockIdx.x;
    for (int i = t; i < NBK; i += 256) h[i] = 0;
    __syncthreads();
    int base = blk * 4096;
    int end = min(base + 4096, E);
    for (int e = base + t; e < end; e += 256) atomicAdd(&h[dst[e] >> 7], 1);
    __syncthreads();
    for (int i = t; i < NBK; i += 256) blkhist[blk * NBK + i] = h[i];
}

// per-bucket: scan over scatter blocks -> bucket-RELATIVE block bases; emit total
__global__ __launch_bounds__(512) void bucket_scan_kernel(
    const int* __restrict__ blkhist, int* __restrict__ bbase,
    int* __restrict__ btotal)
{
    __shared__ int s[512];
    int b = blockIdx.x, t = threadIdx.x;
    int v = (t < NSB) ? blkhist[t * NBK + b] : 0;
    s[t] = v;
    __syncthreads();
#pragma unroll
    for (int off = 1; off < 512; off <<= 1) {
        int u = (t >= off) ? s[t - off] : 0;
        __syncthreads();
        s[t] += u;
        __syncthreads();
    }
    if (t < NSB) bbase[t * NBK + b] = s[t] - v;   // relative to bucket start
    if (t == NSB - 1) btotal[b] = s[t];           // bucket total
}

// single block: exclusive scan of bucket totals in-place; bb[NBK] = E sentinel
__global__ __launch_bounds__(1024) void bucket_base_scan_kernel(int* bb)
{
    __shared__ int s[1024];
    int t = threadIdx.x;
    int v = (t < NBK) ? bb[t] : 0;
    s[t] = v;
    __syncthreads();
#pragma unroll
    for (int off = 1; off < 1024; off <<= 1) {
        int u = (t >= off) ? s[t - off] : 0;
        __syncthreads();
        s[t] += u;
        __syncthreads();
    }
    if (t <= NBK) bb[t] = (t == 0) ? 0 : s[t - 1];
}

__global__ __launch_bounds__(256) void bucket_scatter_kernel(
    const int* __restrict__ src, const int* __restrict__ dst,
    const int* __restrict__ bbase, const int* __restrict__ bucket_base,
    unsigned* __restrict__ staging, int E)
{
    __shared__ int cur[NBK];
    int t = threadIdx.x, blk = blockIdx.x;
    for (int i = t; i < NBK; i += 256)
        cur[i] = bbase[blk * NBK + i] + bucket_base[i];
    __syncthreads();
    int base = blk * 4096;
    int end = min(base + 4096, E);
    for (int e = base + t; e < end; e += 256) {
        int d = dst[e];
        int p = atomicAdd(&cur[d >> 7], 1);
        staging[p] = ((unsigned)src[e] << 7) | (unsigned)(d & 127);
    }
}

// pass 1: LDS-histogram the bucket's 128 node slots -> deg/rowptr; pass 2: fill
__global__ __launch_bounds__(256) void bucket_fill_kernel(
    const unsigned* __restrict__ staging, const int* __restrict__ bucket_base,
    int* __restrict__ rowptr, int* __restrict__ deg_i,
    int* __restrict__ csr_src, int N)
{
    __shared__ int cnt[128];
    __shared__ int sc[128];
    __shared__ int cur[128];
    int b = blockIdx.x;
    int t = threadIdx.x;
    if (t < 128) cnt[t] = 0;
    __syncthreads();
    int start = bucket_base[b];
    int end = bucket_base[b + 1];
    for (int e = start + t; e < end; e += 256)
        atomicAdd(&cnt[staging[e] & 127], 1);
    __syncthreads();
    // exclusive scan over 128 slot counts
    if (t < 128) sc[t] = cnt[t];
    __syncthreads();
#pragma unroll
    for (int off = 1; off < 128; off <<= 1) {
        int v = (t < 128 && t >= off) ? sc[t - off] : 0;
        __syncthreads();
        if (t < 128) sc[t] += v;
        __syncthreads();
    }
    if (t < 128) {
        int excl = sc[t] - cnt[t];
        cur[t] = start + excl;
        int node = (b << 7) + t;
        if (node < N) {
            rowptr[node] = start + excl;
            deg_i[node] = cnt[t];
        }
    }
    __syncthreads();
    for (int e = start + t; e < end; e += 256) {
        unsigned u = staging[e];
        int p = atomicAdd(&cur[u & 127], 1);
        csr_src[p] = (int)(u >> 7);
    }
}

// ---------------- weight transpose+cast: Wt[layer][col][k] bf16 ----------------
__global__ __launch_bounds__(256) void wt_kernel(
    const float* __restrict__ Wl1, const float* __restrict__ Wr1,
    const float* __restrict__ Wl2, const float* __restrict__ Wr2,
    unsigned short* __restrict__ wt)
{
    int e = blockIdx.x * 256 + threadIdx.x;   // 0..65535
    int layer = e >> 15;
    int idx = e & 32767;
    int k = idx >> 7;      // 0..255
    int c = idx & 127;
    const float* W = (layer == 0) ? (k < 128 ? Wl1 : Wr1)
                                  : (k < 128 ? Wl2 : Wr2);
    float v = W[(k & 127) * 128 + c];
    wt[layer * 32768 + c * 256 + k] = f2bf(v);
}

// ---------------- cast x -> bf16 ----------------
__global__ __launch_bounds__(256) void cast_kernel(
    const float* __restrict__ x, unsigned short* __restrict__ xb, int total4)
{
    int i = blockIdx.x * 256 + threadIdx.x;
    if (i >= total4) return;
    float4 v = ((const float4*)x)[i];
    unsigned lo = ((unsigned)f2bf(v.y) << 16) | f2bf(v.x);
    unsigned hi = ((unsigned)f2bf(v.w) << 16) | f2bf(v.z);
    ((uint2*)xb)[i] = make_uint2(lo, hi);
}

// ---------------- aggregate: mean over in-neighbors (bf16 src) ----------------
// 1 node/wave; lane l preloads csr_src[start+l] (up to 64 indices in ONE
// coalesced load per 64-edge block); per-edge indices via __shfl. Quarter-wave
// q handles edge e+q; lane c=(lane&15) loads 16B of the neighbor row.
// Main loop: 16 edges/iter, 4 unchecked gathers (4KB/wave in flight).
// Tail: 4 edges/iter, predicated. Accumulation order per register identical
// to R10 (edges q, q+4, q+8, ...) -> bit-identical output.
__global__ __launch_bounds__(256) void csr_mean_kernel(
    const uint4* __restrict__ featb4, const int* __restrict__ rowptr,
    const int* __restrict__ deg_i, const int* __restrict__ csr_src,
    uint4* __restrict__ mean4, int N)
{
    int n = blockIdx.x * 4 + (threadIdx.x >> 6);
    int lane = threadIdx.x & 63;
    int q = lane >> 4;        // edge slot 0..3
    int c = lane & 15;        // 16B column segment
    if (n >= N) return;
    int start = rowptr[n];
    int dg = deg_i[n];

    float acc[8];
#pragma unroll
    for (int j = 0; j < 8; ++j) acc[j] = 0.f;

    for (int base = 0; base < dg; base += 64) {
        int m = min(dg - base, 64);
        int idx = (lane < m) ? csr_src[start + base + lane] : 0;

        int e = 0;
        for (; e + 16 <= m; e += 16) {
            int i0 = __shfl(idx, e + q);
            int i1 = __shfl(idx, e + 4 + q);
            int i2 = __shfl(idx, e + 8 + q);
            int i3 = __shfl(idx, e + 12 + q);
            uint4 u0 = featb4[(unsigned)((i0 << 4) | c)];
            uint4 u1 = featb4[(unsigned)((i1 << 4) | c)];
            uint4 u2 = featb4[(unsigned)((i2 << 4) | c)];
            uint4 u3 = featb4[(unsigned)((i3 << 4) | c)];
            upadd(u0.x, acc[0], acc[1]);
            upadd(u0.y, acc[2], acc[3]);
            upadd(u0.z, acc[4], acc[5]);
            upadd(u0.w, acc[6], acc[7]);
            upadd(u1.x, acc[0], acc[1]);
            upadd(u1.y, acc[2], acc[3]);
            upadd(u1.z, acc[4], acc[5]);
            upadd(u1.w, acc[6], acc[7]);
            upadd(u2.x, acc[0], acc[1]);
            upadd(u2.y, acc[2], acc[3]);
            upadd(u2.z, acc[4], acc[5]);
            upadd(u2.w, acc[6], acc[7]);
            upadd(u3.x, acc[0], acc[1]);
            upadd(u3.y, acc[2], acc[3]);
            upadd(u3.z, acc[4], acc[5]);
            upadd(u3.w, acc[6], acc[7]);
        }
        for (; e < m; e += 4) {
            int sl = e + q;
            int i0 = __shfl(idx, sl < 64 ? sl : 0);
            uint4 u0 = make_uint4(0, 0, 0, 0);
            if (sl < m) u0 = featb4[(unsigned)((i0 << 4) | c)];
            upadd(u0.x, acc[0], acc[1]);
            upadd(u0.y, acc[2], acc[3]);
            upadd(u0.z, acc[4], acc[5]);
            upadd(u0.w, acc[6], acc[7]);
        }
    }

    // cross-quarter reduction: lanes c, c+16, c+32, c+48 hold partials of cols 8c..8c+7
#pragma unroll
    for (int j = 0; j < 8; ++j) {
        acc[j] += __shfl_xor(acc[j], 16);
        acc[j] += __shfl_xor(acc[j], 32);
    }

    if (q == 0) {
        float r = 1.0f / fmaxf((float)dg, 1.0f);
        uint4 o;
        o.x = ((unsigned)f2bf(acc[1] * r) << 16) | f2bf(acc[0] * r);
        o.y = ((unsigned)f2bf(acc[3] * r) << 16) | f2bf(acc[2] * r);
        o.z = ((unsigned)f2bf(acc[5] * r) << 16) | f2bf(acc[4] * r);
        o.w = ((unsigned)f2bf(acc[7] * r) << 16) | f2bf(acc[6] * r);
        mean4[(unsigned)((n << 5) | c)] = o;
    }
}

// ---------------- MFMA GEMM: out = [mean|x] @ Wt^T + bias (+relu) ----------------
// 256 thr = 4 waves; block computes 64 rows x 128 cols; K=256 in 4 chunks.
// meanb: bf16, row pitch MPITCH (interleaved in d_out). xin: bf16, pitch F.
// Aliasing-safe: block reads ONLY its own rows of meanb/xin; epilogue writes
// those same rows after all reads (ordered by __syncthreads within block).
template <bool RELU, bool OUT_BF16>
__global__ __launch_bounds__(256) void sage_gemm_mfma(
    const unsigned short* __restrict__ meanb,
    const unsigned short* __restrict__ xin,
    const unsigned short* __restrict__ wt,   // [128 cols][256 k] bf16
    const float* __restrict__ bias,
    float* __restrict__ outp, unsigned short* __restrict__ outb, int N)
{
    __shared__ unsigned short As[64][72];    // stride 144 B: 16B-aligned, conflict-free b128
    __shared__ unsigned short Bs[128][72];

    const int t = threadIdx.x;
    const int block_row = blockIdx.x * 64;
    const int lane = t & 63;
    const int w = t >> 6;
    const int m = lane & 15;
    const int kq = lane >> 4;

    f32x4 acc[8];
#pragma unroll
    for (int i = 0; i < 8; ++i) acc[i] = (f32x4){0.f, 0.f, 0.f, 0.f};

    for (int chunk = 0; chunk < 4; ++chunk) {
        const bool is_mean = (chunk < 2);
        const int kbase = (chunk & 1) * 64;

        // ---- A tile: 64 rows x 64 k (each thread: 16 bf16 = 32 B) ----
        {
            int row_l = t >> 2;
            int seg = t & 3;
            int grow = block_row + row_l;
            unsigned short* dstp = &As[row_l][seg * 16];
            if (grow < N) {
                const unsigned short* srcp = is_mean
                    ? meanb + (size_t)grow * MPITCH + kbase + seg * 16
                    : xin   + (size_t)grow * F      + kbase + seg * 16;
                const uint4* p = (const uint4*)srcp;
                ((uint4*)dstp)[0] = p[0];
                ((uint4*)dstp)[1] = p[1];
            } else {
                uint4 z = make_uint4(0, 0, 0, 0);
                ((uint4*)dstp)[0] = z;
                ((uint4*)dstp)[1] = z;
            }
        }
        // ---- B tile: 128 cols x 64 k from Wt (each thread: 32 bf16 = 64 B) ----
        {
            int c = t >> 1;
            int half = t & 1;
            const uint4* p = (const uint4*)(wt + c * 256 + chunk * 64 + half * 32);
            unsigned short* dstp = &Bs[c][half * 32];
            ((uint4*)dstp)[0] = p[0];
            ((uint4*)dstp)[1] = p[1];
            ((uint4*)dstp)[2] = p[2];
            ((uint4*)dstp)[3] = p[3];
        }
        __syncthreads();

        // ---- MFMA: A[m=lane&15][k=(lane>>4)*8+j], B[k][n=lane&15] ----
#pragma unroll
        for (int ks = 0; ks < 2; ++ks) {
            short8 a = *(const short8*)&As[w * 16 + m][ks * 32 + kq * 8];
#pragma unroll
            for (int tt = 0; tt < 8; ++tt) {
                short8 b = *(const short8*)&Bs[tt * 16 + m][ks * 32 + kq * 8];
                acc[tt] = __builtin_amdgcn_mfma_f32_16x16x32_bf16(a, b, acc[tt], 0, 0, 0);
            }
        }
        __syncthreads();
    }

    // ---- epilogue: C/D row=(lane>>4)*4+reg, col=lane&15 ----
    float bb[8];
#pragma unroll
    for (int tt = 0; tt < 8; ++tt) bb[tt] = bias[tt * 16 + m];
    int rbase = block_row + w * 16 + kq * 4;
#pragma unroll
    for (int r = 0; r < 4; ++r) {
        int grow = rbase + r;
        if (grow < N) {
#pragma unroll
            for (int tt = 0; tt < 8; ++tt) {
                float v = acc[tt][r] + bb[tt];
                if (RELU) v = fmaxf(v, 0.f);
                if (OUT_BF16)
                    outb[(size_t)grow * F + tt * 16 + m] = f2bf(v);
                else
                    outp[(size_t)grow * F + tt * 16 + m] = v;
            }
        }
    }
}

extern "C" void kernel_launch(void* const* d_in, const int* in_sizes, int n_in,
                              void* d_out, int out_size, void* d_ws, size_t ws_size,
                              hipStream_t stream) {
    const float* x    = (const float*)d_in[0];
    const int*   ei   = (const int*)d_in[1];    // int32 (harness converts int64)
    const float* W_l1 = (const float*)d_in[2];
    const float* W_r1 = (const float*)d_in[3];
    const float* b1   = (const float*)d_in[4];
    const float* W_l2 = (const float*)d_in[5];
    const float* W_r2 = (const float*)d_in[6];
    const float* b2   = (const float*)d_in[7];
    float* out        = (float*)d_out;

    const int N = N_NODES;
    const int E = N_EDGES;
    const int* srcv = ei;
    const int* dstv = ei + E;

    // ---- workspace layout (bytes); ws_size proven >= 33,337,344 ----
    const size_t rowptr_off = 400128;            // int[N]
    const size_t bb_off     = 800256;            // bucket_base int[NBK+1] (4096 reserved)
    const size_t csr_off    = 804352;            // int[1.6M] = 6.4 MB -> 7,204,352
    const size_t xb_off     = 7204352;           // bf16[N*F] = 25.6 MB -> 32,804,352
    const size_t wt_off     = 32804352;          // bf16[2][128][256] -> 32,935,424
    const size_t need_min   = 32935424;          // < proven 33,337,344
    // transients aliased into xb region (consumed by bucket_fill before cast):
    const size_t blkh_rel   = 0;                 // int[NSB*NBK]
    const size_t bbase_rel  = 1223168;           // int[NSB*NBK]
    const size_t stag_rel   = 2446336;           // uint[1.6M] -> 8,846,336 (< 25.6MB)

    if (ws_size < need_min) return;  // clean validation failure as diagnostic

    char* ws = (char*)d_ws;
    int* deg_i   = (int*)ws;
    int* rowptr  = (int*)(ws + rowptr_off);
    int* bucket_base = (int*)(ws + bb_off);
    int* csr_src = (int*)(ws + csr_off);
    unsigned short* xb = (unsigned short*)(ws + xb_off);
    int* blkhist = (int*)(ws + xb_off + blkh_rel);
    int* bbase   = (int*)(ws + xb_off + bbase_rel);
    unsigned* staging = (unsigned*)(ws + xb_off + stag_rel);
    unsigned short* wt = (unsigned short*)(ws + wt_off);
    // means live interleaved in d_out: row n -> bytes [n*512, n*512+256)
    uint4* mean4 = (uint4*)d_out;
    const unsigned short* meanb = (const unsigned short*)d_out;

    // ---- contention-free bucket permute -> csr_src (+deg/rowptr fused) ----
    blkhist_kernel<<<dim3(NSB), dim3(256), 0, stream>>>(dstv, blkhist, E);
    bucket_scan_kernel<<<dim3(NBK), dim3(512), 0, stream>>>(blkhist, bbase, bucket_base);
    bucket_base_scan_kernel<<<dim3(1), dim3(1024), 0, stream>>>(bucket_base);
    bucket_scatter_kernel<<<dim3(NSB), dim3(256), 0, stream>>>(
        srcv, dstv, bbase, bucket_base, staging, E);
    bucket_fill_kernel<<<dim3(NBK), dim3(256), 0, stream>>>(
        staging, bucket_base, rowptr, deg_i, csr_src, N);

    // ---- weight prep + x cast (after staging consumed) ----
    wt_kernel<<<dim3(256), dim3(256), 0, stream>>>(W_l1, W_r1, W_l2, W_r2, wt);
    cast_kernel<<<dim3((N * F / 4 + 255) / 256), dim3(256), 0, stream>>>(x, xb, N * F / 4);

    dim3 ablock(256), agrid((N + 3) / 4);
    dim3 gblock(256), ggrid((N + 63) / 64);

    // ---- layer 1: mean1(xb) -> d_out interleaved; gemm1 -> h bf16 into xb ----
    csr_mean_kernel<<<agrid, ablock, 0, stream>>>(
        (const uint4*)xb, rowptr, deg_i, csr_src, mean4, N);
    sage_gemm_mfma<true, true><<<ggrid, gblock, 0, stream>>>(
        meanb, xb, wt, b1, nullptr, xb, N);

    // ---- layer 2: mean2(xb=h) -> d_out interleaved; gemm2 -> fp32 d_out ----
    csr_mean_kernel<<<agrid, ablock, 0, stream>>>(
        (const uint4*)xb, rowptr, deg_i, csr_src, mean4, N);
    sage_gemm_mfma<false, false><<<ggrid, gblock, 0, stream>>>(
        meanb, xb, wt + 32768, b2, out, nullptr, N);
}